// Round 1
// baseline (710.574 us; speedup 1.0000x reference)
//
#include <hip/hip_runtime.h>
#include <cstdint>

// Problem constants (fixed by setup_inputs)
constexpr int kB  = 2;
constexpr int kN  = 21760;
constexpr int kC  = 256;
constexpr int kL  = 4;
constexpr int kH  = 8;
constexpr int kP  = 4;
constexpr int kD  = 32;      // Dh = C / Hh
constexpr int kS  = 21760;   // sum of level areas
constexpr int kM  = kB * kN; // 43520 rows for the query-side GEMMs

// ---------------------------------------------------------------------------
// Simple tiled f32 GEMM with bias: C[M,Nn] = A[M,K] @ W[K,Nn] + bias[Nn]
// 64x64 tile, 256 threads, 4x4 accumulators per thread, K-step 16.
// All dims here are exact multiples of the tile (M=43520=680*64, Nn in {128,256},
// K=256), so no bounds checks.
// ---------------------------------------------------------------------------
#define TK 16
#define TM 64
#define TN 64

__global__ __launch_bounds__(256) void gemm_bias_f32(
    const float* __restrict__ A, const float* __restrict__ W,
    const float* __restrict__ bias, float* __restrict__ C,
    int M, int Nn, int K)
{
  __shared__ float As[TK][TM + 4];  // [k][m], +4 pad keeps 16B alignment
  __shared__ float Bs[TK][TN + 4];  // [k][n]

  const int t  = threadIdx.x;
  const int m0 = blockIdx.x * TM;
  const int n0 = blockIdx.y * TN;
  const int tx = t & 15;
  const int ty = t >> 4;

  // global->LDS load mapping
  const int arow = t >> 2;         // 0..63
  const int akc  = (t & 3) << 2;   // 0,4,8,12
  const int bkk  = t >> 4;         // 0..15
  const int bnc  = (t & 15) << 2;  // 0..60

  float acc[4][4] = {};

  for (int kt = 0; kt < K; kt += TK) {
    const float4 a4 = *(const float4*)&A[(size_t)(m0 + arow) * K + kt + akc];
    const float4 b4 = *(const float4*)&W[(size_t)(kt + bkk) * Nn + n0 + bnc];
    As[akc + 0][arow] = a4.x;
    As[akc + 1][arow] = a4.y;
    As[akc + 2][arow] = a4.z;
    As[akc + 3][arow] = a4.w;
    *(float4*)&Bs[bkk][bnc] = b4;
    __syncthreads();
#pragma unroll
    for (int kk = 0; kk < TK; ++kk) {
      const float4 av = *(const float4*)&As[kk][ty << 2];
      const float4 bv = *(const float4*)&Bs[kk][tx << 2];
      const float aa[4] = {av.x, av.y, av.z, av.w};
      const float bb[4] = {bv.x, bv.y, bv.z, bv.w};
#pragma unroll
      for (int i = 0; i < 4; ++i)
#pragma unroll
        for (int j = 0; j < 4; ++j)
          acc[i][j] = fmaf(aa[i], bb[j], acc[i][j]);
    }
    __syncthreads();
  }

  const float4 bias4 = *(const float4*)&bias[n0 + (tx << 2)];
  const float bb[4] = {bias4.x, bias4.y, bias4.z, bias4.w};
#pragma unroll
  for (int i = 0; i < 4; ++i) {
    const int row = m0 + (ty << 2) + i;
    float4 o;
    o.x = acc[i][0] + bb[0];
    o.y = acc[i][1] + bb[1];
    o.z = acc[i][2] + bb[2];
    o.w = acc[i][3] + bb[3];
    *(float4*)&C[(size_t)row * Nn + n0 + (tx << 2)] = o;
  }
}

// ---------------------------------------------------------------------------
// MSDA core: one block per query (b,n). 256 threads = 8 heads x 32 channels.
// Thread t: h = t>>5, d = t&31. Softmax over the head's 16 logits in
// registers (loads broadcast across the 32-lane channel group), then 16
// bilinear samples; each corner gather is a coalesced 128B read across the
// channel group. Zero-padding semantics: load at clipped index, multiply by
// validity — matches the reference exactly.
// ---------------------------------------------------------------------------
__global__ __launch_bounds__(256) void msda_kernel(
    const float* __restrict__ off_buf,   // [M,256] = (b,n,h,l,p,2)
    const float* __restrict__ attn_buf,  // [M,128] = (b,n,h,l*p) raw logits
    const float* __restrict__ value,     // [M,256] = (b,s,h,d)
    const float* __restrict__ priors,    // [M,8]   = (b,n,l,2)
    float* __restrict__ wout)            // [M,256] = (b,n,h,d)
{
  const int q = blockIdx.x;       // 0..kM-1
  const int b = q / kN;
  const int t = threadIdx.x;
  const int h = t >> 5;
  const int d = t & 31;

  // --- softmax over 16 logits (per head) ---
  const float* lg = attn_buf + (size_t)q * 128 + h * 16;
  float p[16];
  float mx = -1e30f;
#pragma unroll
  for (int j = 0; j < 16; ++j) { p[j] = lg[j]; mx = fmaxf(mx, p[j]); }
  float sum = 0.f;
#pragma unroll
  for (int j = 0; j < 16; ++j) { p[j] = __expf(p[j] - mx); sum += p[j]; }
  const float inv = 1.f / sum;

  const float* offp = off_buf + (size_t)q * 256 + h * 32;
  const float* prp  = priors + (size_t)q * 8;
  const float* vb   = value + (size_t)b * kS * kC + h * kD + d;

  const int WA[4] = {128, 64, 32, 16};
  const int SA[4] = {0, 16384, 20480, 21504};

  float acc = 0.f;
#pragma unroll
  for (int lv = 0; lv < kL; ++lv) {
    const int Wl = WA[lv];
    const int Hl = WA[lv];
    const float fW = (float)Wl, fH = (float)Hl;
    const float px = prp[lv * 2 + 0];
    const float py = prp[lv * 2 + 1];
    const float* vl = vb + (size_t)SA[lv] * kC;
#pragma unroll
    for (int pp = 0; pp < kP; ++pp) {
      const int j = lv * 4 + pp;
      const float ox = offp[j * 2 + 0];
      const float oy = offp[j * 2 + 1];
      const float lx = (px + ox / fW) * fW - 0.5f;
      const float ly = (py + oy / fH) * fH - 0.5f;
      const float x0f = floorf(lx), y0f = floorf(ly);
      const float wx1 = lx - x0f, wy1 = ly - y0f;
      const float wx0 = 1.f - wx1, wy0 = 1.f - wy1;
      const int x0 = (int)x0f, y0 = (int)y0f;

      auto corner = [&](int xi, int yi) -> float {
        const int xc = min(max(xi, 0), Wl - 1);
        const int yc = min(max(yi, 0), Hl - 1);
        const float g = vl[(size_t)(yc * Wl + xc) * kC];
        const bool ok = (xi >= 0) & (xi < Wl) & (yi >= 0) & (yi < Hl);
        return ok ? g : 0.f;
      };

      const float bil = corner(x0,     y0    ) * (wx0 * wy0)
                      + corner(x0 + 1, y0    ) * (wx1 * wy0)
                      + corner(x0,     y0 + 1) * (wx0 * wy1)
                      + corner(x0 + 1, y0 + 1) * (wx1 * wy1);
      acc += p[j] * bil;
    }
  }

  wout[(size_t)q * 256 + t] = acc * inv;
}

// ---------------------------------------------------------------------------
// launch
// ---------------------------------------------------------------------------
extern "C" void kernel_launch(void* const* d_in, const int* in_sizes, int n_in,
                              void* d_out, int out_size, void* d_ws, size_t ws_size,
                              hipStream_t stream) {
  const float* in_feats = (const float*)d_in[0];   // [B,N,C]
  const float* priors   = (const float*)d_in[1];   // [B,N,L,2]
  const float* sfeats   = (const float*)d_in[2];   // [B,S,C]
  // d_in[3] shapes, d_in[4] start_ids: compile-time constants here
  const float* W_off  = (const float*)d_in[5];
  const float* b_off  = (const float*)d_in[6];
  const float* W_attn = (const float*)d_in[7];
  const float* b_attn = (const float*)d_in[8];
  const float* W_val  = (const float*)d_in[9];
  const float* b_val  = (const float*)d_in[10];
  const float* W_out  = (const float*)d_in[11];
  const float* b_out  = (const float*)d_in[12];
  float* out = (float*)d_out;

  // workspace layout (all fully written before read; ~149 MB)
  float* off_buf  = (float*)d_ws;                  // kM*256
  float* attn_buf = off_buf + (size_t)kM * 256;    // kM*128
  float* val_buf  = attn_buf + (size_t)kM * 128;   // kM*256
  float* wgt_buf  = val_buf + (size_t)kM * 256;    // kM*256

  const dim3 blk(256);
  const int mtiles = kM / TM;  // 680

  gemm_bias_f32<<<dim3(mtiles, 256 / TN), blk, 0, stream>>>(
      in_feats, W_off, b_off, off_buf, kM, 256, kC);
  gemm_bias_f32<<<dim3(mtiles, 128 / TN), blk, 0, stream>>>(
      in_feats, W_attn, b_attn, attn_buf, kM, 128, kC);
  gemm_bias_f32<<<dim3(mtiles, 256 / TN), blk, 0, stream>>>(
      sfeats, W_val, b_val, val_buf, kM, 256, kC);

  msda_kernel<<<dim3(kM), blk, 0, stream>>>(off_buf, attn_buf, val_buf, priors, wgt_buf);

  gemm_bias_f32<<<dim3(mtiles, 256 / TN), blk, 0, stream>>>(
      wgt_buf, W_out, b_out, out, kM, 256, kC);
}

// Round 2
// 278.391 us; speedup vs baseline: 2.5524x; 2.5524x over previous
//
#include <hip/hip_runtime.h>
#include <cstdint>

// Problem constants (fixed by setup_inputs)
constexpr int kB = 2;
constexpr int kN = 21760;
constexpr int kC = 256;
constexpr int kH = 8;
constexpr int kS = 21760;    // total sample-map area
constexpr int kM = kB * kN;  // 43520 rows

typedef __attribute__((ext_vector_type(8))) short bf16x8;   // MFMA A/B frag (4 VGPR)
typedef __attribute__((ext_vector_type(4))) float f32x4;    // MFMA C/D frag
typedef __attribute__((ext_vector_type(8))) unsigned short us8;

__device__ __forceinline__ float bf2f(unsigned short u) {
  return __uint_as_float(((unsigned int)u) << 16);
}
__device__ __forceinline__ unsigned short f2bf(float f) {
  unsigned int u = __float_as_uint(f);
  u += 0x7fffu + ((u >> 16) & 1u);
  return (unsigned short)(u >> 16);
}
__device__ __forceinline__ void gld_lds16(const unsigned short* g, unsigned short* l) {
  __builtin_amdgcn_global_load_lds(
      (const __attribute__((address_space(1))) unsigned int*)g,
      (__attribute__((address_space(3))) unsigned int*)l, 16, 0, 0);
}

// ---------------------------------------------------------------------------
// Convert in_feats & sfeats f32 [kM][256] -> bf16, rows pre-swizzled for the
// GEMM LDS tile: element k goes to k ^ ((m&7)<<3)  (8-element groups, XOR on
// bits 3-5 => stays within each 64-k block; inverse == forward).
// ---------------------------------------------------------------------------
__global__ __launch_bounds__(256) void convert_act(
    const float* __restrict__ a, const float* __restrict__ b,
    unsigned short* __restrict__ da, unsigned short* __restrict__ db)
{
  const int tid = blockIdx.x * 256 + threadIdx.x;
  const int half = kM * 32;
  const float* src; unsigned short* dst; int id;
  if (tid < half) { src = a; dst = da; id = tid; }
  else            { src = b; dst = db; id = tid - half; }
  const int m = id >> 5;
  const int kb = (id & 31) * 8;
  const float4 x0 = *(const float4*)&src[(size_t)m * 256 + kb];
  const float4 x1 = *(const float4*)&src[(size_t)m * 256 + kb + 4];
  us8 o;
  o[0] = f2bf(x0.x); o[1] = f2bf(x0.y); o[2] = f2bf(x0.z); o[3] = f2bf(x0.w);
  o[4] = f2bf(x1.x); o[5] = f2bf(x1.y); o[6] = f2bf(x1.z); o[7] = f2bf(x1.w);
  *(us8*)&dst[(size_t)m * 256 + (kb ^ ((m & 7) << 3))] = o;
}

// ---------------------------------------------------------------------------
// Weights: f32 [K=256][N] -> bf16 transposed [N][K], rows pre-swizzled
// (same XOR) so the GEMM can stage them identically to A.
// Handles all 4 weight matrices in one launch (row ranges).
// ---------------------------------------------------------------------------
__global__ __launch_bounds__(256) void prep_weights(
    const float* __restrict__ Woff, const float* __restrict__ Wattn,
    const float* __restrict__ Wval, const float* __restrict__ Wout,
    unsigned short* __restrict__ BtOff, unsigned short* __restrict__ BtAttn,
    unsigned short* __restrict__ BtVal, unsigned short* __restrict__ BtOut)
{
  const int tid = blockIdx.x * 256 + threadIdx.x;   // 896 rows * 32
  const int r = tid >> 5;
  const int kb = (tid & 31) * 8;
  const float* W; unsigned short* Bt; int n, Nn;
  if (r < 256)      { W = Woff;  Bt = BtOff;  n = r;       Nn = 256; }
  else if (r < 384) { W = Wattn; Bt = BtAttn; n = r - 256; Nn = 128; }
  else if (r < 640) { W = Wval;  Bt = BtVal;  n = r - 384; Nn = 256; }
  else              { W = Wout;  Bt = BtOut;  n = r - 640; Nn = 256; }
  us8 o;
#pragma unroll
  for (int i = 0; i < 8; ++i) o[i] = f2bf(W[(size_t)(kb + i) * Nn + n]);
  *(us8*)&Bt[(size_t)n * 256 + (kb ^ ((n & 7) << 3))] = o;
}

// ---------------------------------------------------------------------------
// bf16 MFMA GEMM: C[M,Nn] = A[M,256] @ Bt[Nn,256]^T + bias.
// A and Bt are bf16 with pre-swizzled rows. 128x128 tile, BK=64, 4 waves
// (2x2), each wave 4x4 fragments of 16x16x32. Staging via global_load_lds
// width 16 into linear LDS; fragment ds_read_b128 at swizzled offsets
// (2-way bank aliasing only).
// OMODE: 0 = f32 out, 1 = bf16 plain out.
// ---------------------------------------------------------------------------
template <int OMODE>
__global__ __launch_bounds__(256) void gemm_bf16(
    const unsigned short* __restrict__ A,
    const unsigned short* __restrict__ Bt,
    const float* __restrict__ bias,
    void* __restrict__ Cout, int Nn)
{
  __shared__ unsigned short As[128 * 64];
  __shared__ unsigned short Bs[128 * 64];
  const int t = threadIdx.x;
  const int w = t >> 6, l = t & 63;
  const int m0 = blockIdx.x * 128, n0 = blockIdx.y * 128;
  const int wm = w >> 1, wn = w & 1;

  f32x4 acc[4][4] = {};

  const int srow = l >> 3;        // staging row within chunk
  const int skb  = (l & 7) * 8;   // ushort offset within 64-k block

  for (int kt = 0; kt < 256; kt += 64) {
#pragma unroll
    for (int i = 0; i < 4; ++i) {
      const int c = i * 4 + w;          // chunk: 8 rows, 1 KiB
      const int row = c * 8 + srow;
      gld_lds16(A + (size_t)(m0 + row) * 256 + kt + skb, &As[c * 512]);
    }
#pragma unroll
    for (int i = 0; i < 4; ++i) {
      const int c = i * 4 + w;
      const int row = c * 8 + srow;
      gld_lds16(Bt + (size_t)(n0 + row) * 256 + kt + skb, &Bs[c * 512]);
    }
    __syncthreads();   // compiler drains vmcnt before s_barrier

#pragma unroll
    for (int s = 0; s < 2; ++s) {
      bf16x8 af[4], bfr[4];
      const int kf = s * 32 + ((l >> 4) * 8);
#pragma unroll
      for (int i = 0; i < 4; ++i) {
        const int row = wm * 64 + i * 16 + (l & 15);
        af[i] = *(const bf16x8*)&As[row * 64 + (kf ^ ((row & 7) << 3))];
      }
#pragma unroll
      for (int j = 0; j < 4; ++j) {
        const int col = wn * 64 + j * 16 + (l & 15);
        bfr[j] = *(const bf16x8*)&Bs[col * 64 + (kf ^ ((col & 7) << 3))];
      }
#pragma unroll
      for (int i = 0; i < 4; ++i)
#pragma unroll
        for (int j = 0; j < 4; ++j)
          acc[i][j] = __builtin_amdgcn_mfma_f32_16x16x32_bf16(af[i], bfr[j], acc[i][j], 0, 0, 0);
    }
    __syncthreads();
  }

  // epilogue: C/D map col = lane&15, row = (lane>>4)*4 + reg  [m89-verified]
  const int lr = l >> 4;
#pragma unroll
  for (int j = 0; j < 4; ++j) {
    const int col = n0 + wn * 64 + j * 16 + (l & 15);
    const float bv = bias[col];
#pragma unroll
    for (int i = 0; i < 4; ++i) {
      const int rbase = m0 + wm * 64 + i * 16 + lr * 4;
#pragma unroll
      for (int r = 0; r < 4; ++r) {
        const float v = acc[i][j][r] + bv;
        if (OMODE == 0) ((float*)Cout)[(size_t)(rbase + r) * Nn + col] = v;
        else ((unsigned short*)Cout)[(size_t)(rbase + r) * Nn + col] = f2bf(v);
      }
    }
  }
}

// ---------------------------------------------------------------------------
// MSDA core, restructured. Block = 2 queries, 256 threads.
// Phase 1: thread t owns item (qq,h,j): softmax over 16 samples via
//   16-lane shfl_xor; folds attn weight * bilinear weight * validity into
//   4 (corner element-offset, weight) pairs in LDS.
// Phase 2: thread (qq,h,d2) accumulates 16 samples x 4 corners, each a
//   bf16x2 gather; writes wgt bf16 with swizzled rows (A of the out-GEMM).
// ---------------------------------------------------------------------------
__global__ __launch_bounds__(256) void msda_kernel(
    const unsigned short* __restrict__ off_bf,   // [kM][256] bf16 plain
    const unsigned short* __restrict__ attn_bf,  // [kM][128] bf16 plain
    const unsigned short* __restrict__ val_bf,   // [kM][256] bf16 plain
    const float* __restrict__ priors,            // [kM][8]
    unsigned short* __restrict__ wgt)            // [kM][256] bf16 swizzled
{
  __shared__ int   s_off[256 * 4];
  __shared__ float s_w[256 * 4];
  const int q0 = blockIdx.x * 2;
  const int t = threadIdx.x;

  { // ---- phase 1: per-(q,h,sample) metadata ----
    const int qq = t >> 7, hj = t & 127, j = t & 15;
    const int q = q0 + qq;
    const int lv = j >> 2;

    const float lgt = bf2f(attn_bf[(size_t)q * 128 + hj]);
    float mx = lgt;
#pragma unroll
    for (int m = 8; m; m >>= 1) mx = fmaxf(mx, __shfl_xor(mx, m, 16));
    const float p = __expf(lgt - mx);
    float sum = p;
#pragma unroll
    for (int m = 8; m; m >>= 1) sum += __shfl_xor(sum, m, 16);
    const float wN = p / sum;

    const unsigned int oo = *(const unsigned int*)&off_bf[(size_t)q * 256 + hj * 2];
    const float ox = bf2f((unsigned short)(oo & 0xffff));
    const float oy = bf2f((unsigned short)(oo >> 16));
    const float2 pr = *(const float2*)&priors[(size_t)q * 8 + lv * 2];

    const int Wl = 128 >> lv;
    const float fW = (float)Wl;
    const float lx = fmaf(pr.x, fW, ox) - 0.5f;
    const float ly = fmaf(pr.y, fW, oy) - 0.5f;
    const float x0f = floorf(lx), y0f = floorf(ly);
    const float wx1 = lx - x0f, wy1 = ly - y0f;
    const float wx0 = 1.f - wx1, wy0 = 1.f - wy1;
    const int x0 = (int)x0f, y0 = (int)y0f;
    const int start = (int)((0x5400500040000000ull >> (16 * lv)) & 0xffff); // {0,16384,20480,21504}

#pragma unroll
    for (int c = 0; c < 4; ++c) {
      const int xi = x0 + (c & 1), yi = y0 + (c >> 1);
      const bool ok = (xi >= 0) & (xi < Wl) & (yi >= 0) & (yi < Wl);
      const int xc = min(max(xi, 0), Wl - 1);
      const int yc = min(max(yi, 0), Wl - 1);
      const float wb = ((c & 1) ? wx1 : wx0) * ((c >> 1) ? wy1 : wy0);
      s_off[t * 4 + c] = (start + yc * Wl + xc) * 256;   // element offset into value rows
      s_w[t * 4 + c] = ok ? wN * wb : 0.f;
    }
  }
  __syncthreads();

  // ---- phase 2: gather + weighted sum ----
  const int qq = t >> 7, h = (t >> 4) & 7, d2 = t & 15;
  const int q = q0 + qq;
  const int b = (q >= kN) ? 1 : 0;
  const unsigned short* vb = val_bf + (size_t)b * kS * 256 + h * 32 + d2 * 2;
  const int ibase = qq * 128 + h * 16;

  float accx = 0.f, accy = 0.f;
#pragma unroll
  for (int j = 0; j < 16; ++j) {
    const int4   o4 = *(const int4*)&s_off[(ibase + j) * 4];
    const float4 w4 = *(const float4*)&s_w[(ibase + j) * 4];
    const int   ofs[4] = {o4.x, o4.y, o4.z, o4.w};
    const float wts[4] = {w4.x, w4.y, w4.z, w4.w};
#pragma unroll
    for (int c = 0; c < 4; ++c) {
      const unsigned int v = *(const unsigned int*)&vb[ofs[c]];
      accx = fmaf(wts[c], bf2f((unsigned short)(v & 0xffff)), accx);
      accy = fmaf(wts[c], bf2f((unsigned short)(v >> 16)), accy);
    }
  }
  const int c0 = h * 32 + d2 * 2;
  const unsigned int packed = (unsigned int)f2bf(accx) | ((unsigned int)f2bf(accy) << 16);
  *(unsigned int*)&wgt[(size_t)q * 256 + (c0 ^ ((q & 7) << 3))] = packed;
}

// ---------------------------------------------------------------------------
// launch
// ---------------------------------------------------------------------------
extern "C" void kernel_launch(void* const* d_in, const int* in_sizes, int n_in,
                              void* d_out, int out_size, void* d_ws, size_t ws_size,
                              hipStream_t stream) {
  const float* in_feats = (const float*)d_in[0];
  const float* priors   = (const float*)d_in[1];
  const float* sfeats   = (const float*)d_in[2];
  const float* W_off  = (const float*)d_in[5];
  const float* b_off  = (const float*)d_in[6];
  const float* W_attn = (const float*)d_in[7];
  const float* b_attn = (const float*)d_in[8];
  const float* W_val  = (const float*)d_in[9];
  const float* b_val  = (const float*)d_in[10];
  const float* W_out  = (const float*)d_in[11];
  const float* b_out  = (const float*)d_in[12];
  float* out = (float*)d_out;

  // workspace (bf16 ushorts), ~123 MB total
  unsigned short* in_bf   = (unsigned short*)d_ws;          // kM*256 (swizzled)
  unsigned short* s_bf    = in_bf   + (size_t)kM * 256;     // kM*256 (swizzled)
  unsigned short* off_bf  = s_bf    + (size_t)kM * 256;     // kM*256 (plain)
  unsigned short* attn_bf = off_bf  + (size_t)kM * 256;     // kM*128 (plain)
  unsigned short* val_bf  = attn_bf + (size_t)kM * 128;     // kM*256 (plain)
  unsigned short* wgt_bf  = val_bf  + (size_t)kM * 256;     // kM*256 (swizzled)
  unsigned short* BtOff   = wgt_bf  + (size_t)kM * 256;     // 256*256
  unsigned short* BtAttn  = BtOff   + 256 * 256;            // 128*256
  unsigned short* BtVal   = BtAttn  + 128 * 256;            // 256*256
  unsigned short* BtOut   = BtVal   + 256 * 256;            // 256*256

  const dim3 blk(256);

  convert_act<<<dim3(kM * 32 * 2 / 256), blk, 0, stream>>>(in_feats, sfeats, in_bf, s_bf);
  prep_weights<<<dim3(896 * 32 / 256), blk, 0, stream>>>(
      W_off, W_attn, W_val, W_out, BtOff, BtAttn, BtVal, BtOut);

  gemm_bf16<1><<<dim3(kM / 128, 2), blk, 0, stream>>>(in_bf, BtOff, b_off, off_bf, 256);
  gemm_bf16<1><<<dim3(kM / 128, 1), blk, 0, stream>>>(in_bf, BtAttn, b_attn, attn_bf, 128);
  gemm_bf16<1><<<dim3(kM / 128, 2), blk, 0, stream>>>(s_bf, BtVal, b_val, val_bf, 256);

  msda_kernel<<<dim3(kM / 2), blk, 0, stream>>>(off_bf, attn_bf, val_bf, priors, wgt_bf);

  gemm_bf16<0><<<dim3(kM / 128, 2), blk, 0, stream>>>(wgt_bf, BtOut, b_out, out, 256);
}

// Round 3
// 180.134 us; speedup vs baseline: 3.9447x; 1.5455x over previous
//
#include <hip/hip_runtime.h>
#include <cstdint>

// Problem constants (fixed by setup_inputs)
constexpr int kB = 2;
constexpr int kN = 21760;
constexpr int kC = 256;
constexpr int kH = 8;
constexpr int kS = 21760;    // total sample-map area
constexpr int kM = kB * kN;  // 43520 rows

typedef __attribute__((ext_vector_type(8))) short bf16x8;   // MFMA A/B frag (4 VGPR)
typedef __attribute__((ext_vector_type(4))) float f32x4;    // MFMA C/D frag
typedef __attribute__((ext_vector_type(8))) unsigned short us8;

__device__ __forceinline__ float bf2f(unsigned short u) {
  return __uint_as_float(((unsigned int)u) << 16);
}
__device__ __forceinline__ unsigned short f2bf(float f) {
  unsigned int u = __float_as_uint(f);
  u += 0x7fffu + ((u >> 16) & 1u);
  return (unsigned short)(u >> 16);
}
__device__ __forceinline__ void gld_lds16(const unsigned short* g, unsigned short* l) {
  __builtin_amdgcn_global_load_lds(
      (const __attribute__((address_space(1))) unsigned int*)g,
      (__attribute__((address_space(3))) unsigned int*)l, 16, 0, 0);
}

// ---------------------------------------------------------------------------
// Convert in_feats & sfeats f32 [kM][256] -> bf16, rows pre-swizzled for the
// GEMM LDS tile: element k goes to k ^ ((m&7)<<3).
// ---------------------------------------------------------------------------
__global__ __launch_bounds__(256) void convert_act(
    const float* __restrict__ a, const float* __restrict__ b,
    unsigned short* __restrict__ da, unsigned short* __restrict__ db)
{
  const int tid = blockIdx.x * 256 + threadIdx.x;
  const int half = kM * 32;
  const float* src; unsigned short* dst; int id;
  if (tid < half) { src = a; dst = da; id = tid; }
  else            { src = b; dst = db; id = tid - half; }
  const int m = id >> 5;
  const int kb = (id & 31) * 8;
  const float4 x0 = *(const float4*)&src[(size_t)m * 256 + kb];
  const float4 x1 = *(const float4*)&src[(size_t)m * 256 + kb + 4];
  us8 o;
  o[0] = f2bf(x0.x); o[1] = f2bf(x0.y); o[2] = f2bf(x0.z); o[3] = f2bf(x0.w);
  o[4] = f2bf(x1.x); o[5] = f2bf(x1.y); o[6] = f2bf(x1.z); o[7] = f2bf(x1.w);
  *(us8*)&dst[(size_t)m * 256 + (kb ^ ((m & 7) << 3))] = o;
}

// ---------------------------------------------------------------------------
// Weights: f32 [K=256][N] -> bf16 transposed [N][K], rows pre-swizzled.
// ---------------------------------------------------------------------------
__global__ __launch_bounds__(256) void prep_weights(
    const float* __restrict__ Woff, const float* __restrict__ Wattn,
    const float* __restrict__ Wval, const float* __restrict__ Wout,
    unsigned short* __restrict__ BtOff, unsigned short* __restrict__ BtAttn,
    unsigned short* __restrict__ BtVal, unsigned short* __restrict__ BtOut)
{
  const int tid = blockIdx.x * 256 + threadIdx.x;   // 896 rows * 32
  const int r = tid >> 5;
  const int kb = (tid & 31) * 8;
  const float* W; unsigned short* Bt; int n, Nn;
  if (r < 256)      { W = Woff;  Bt = BtOff;  n = r;       Nn = 256; }
  else if (r < 384) { W = Wattn; Bt = BtAttn; n = r - 256; Nn = 128; }
  else if (r < 640) { W = Wval;  Bt = BtVal;  n = r - 384; Nn = 256; }
  else              { W = Wout;  Bt = BtOut;  n = r - 640; Nn = 256; }
  us8 o;
#pragma unroll
  for (int i = 0; i < 8; ++i) o[i] = f2bf(W[(size_t)(kb + i) * Nn + n]);
  *(us8*)&Bt[(size_t)n * 256 + (kb ^ ((n & 7) << 3))] = o;
}

// ---------------------------------------------------------------------------
// bf16 MFMA GEMM: C[M,Nn] = A[M,256] @ Bt[Nn,256]^T + bias.
// OMODE: 0 = f32 plain out, 1 = bf16 plain out, 2 = bf16 head-major value
// layout [b, h, s, d] (b = row/kS, s = row%kS, h = col>>5, d = col&31).
// ---------------------------------------------------------------------------
template <int OMODE>
__global__ __launch_bounds__(256) void gemm_bf16(
    const unsigned short* __restrict__ A,
    const unsigned short* __restrict__ Bt,
    const float* __restrict__ bias,
    void* __restrict__ Cout, int Nn)
{
  __shared__ unsigned short As[128 * 64];
  __shared__ unsigned short Bs[128 * 64];
  const int t = threadIdx.x;
  const int w = t >> 6, l = t & 63;
  const int m0 = blockIdx.x * 128, n0 = blockIdx.y * 128;
  const int wm = w >> 1, wn = w & 1;

  f32x4 acc[4][4] = {};

  const int srow = l >> 3;
  const int skb  = (l & 7) * 8;

  for (int kt = 0; kt < 256; kt += 64) {
#pragma unroll
    for (int i = 0; i < 4; ++i) {
      const int c = i * 4 + w;
      const int row = c * 8 + srow;
      gld_lds16(A + (size_t)(m0 + row) * 256 + kt + skb, &As[c * 512]);
    }
#pragma unroll
    for (int i = 0; i < 4; ++i) {
      const int c = i * 4 + w;
      const int row = c * 8 + srow;
      gld_lds16(Bt + (size_t)(n0 + row) * 256 + kt + skb, &Bs[c * 512]);
    }
    __syncthreads();

#pragma unroll
    for (int s = 0; s < 2; ++s) {
      bf16x8 af[4], bfr[4];
      const int kf = s * 32 + ((l >> 4) * 8);
#pragma unroll
      for (int i = 0; i < 4; ++i) {
        const int row = wm * 64 + i * 16 + (l & 15);
        af[i] = *(const bf16x8*)&As[row * 64 + (kf ^ ((row & 7) << 3))];
      }
#pragma unroll
      for (int j = 0; j < 4; ++j) {
        const int col = wn * 64 + j * 16 + (l & 15);
        bfr[j] = *(const bf16x8*)&Bs[col * 64 + (kf ^ ((col & 7) << 3))];
      }
#pragma unroll
      for (int i = 0; i < 4; ++i)
#pragma unroll
        for (int j = 0; j < 4; ++j)
          acc[i][j] = __builtin_amdgcn_mfma_f32_16x16x32_bf16(af[i], bfr[j], acc[i][j], 0, 0, 0);
    }
    __syncthreads();
  }

  // epilogue: C/D map col = lane&15, row = (lane>>4)*4 + reg
  const int lr = l >> 4;
#pragma unroll
  for (int j = 0; j < 4; ++j) {
    const int col = n0 + wn * 64 + j * 16 + (l & 15);
    const float bv = bias[col];
#pragma unroll
    for (int i = 0; i < 4; ++i) {
      const int rbase = m0 + wm * 64 + i * 16 + lr * 4;
#pragma unroll
      for (int r = 0; r < 4; ++r) {
        const float v = acc[i][j][r] + bv;
        if (OMODE == 0) {
          ((float*)Cout)[(size_t)(rbase + r) * Nn + col] = v;
        } else if (OMODE == 1) {
          ((unsigned short*)Cout)[(size_t)(rbase + r) * Nn + col] = f2bf(v);
        } else {
          const int row = rbase + r;
          const int bb = row >= kS;
          const int s2 = row - bb * kS;
          ((unsigned short*)Cout)[((size_t)(bb * 8 + (col >> 5)) * kS + s2) * 32 + (col & 31)] = f2bf(v);
        }
      }
    }
  }
}

// ---------------------------------------------------------------------------
// MSDA core. Block = 2 queries, 256 threads.
// Phase 1: thread t = (qh = t>>4, j = t&15): softmax over 16 logits via
//   16-lane shfl_xor; emits per-sample record {off_top, off_bot, dx} +
//   4 folded weights (attn * bilinear * validity) into LDS at slot
//   j*16 + (qh ^ (j&3))  (conflict-free phase-2 reads).
// Phase 2: thread t = (qh, idx = t&15): xsel = idx>>3 picks the x-corner,
//   ch8 = idx&7 picks 4 channels (8B). Per sample: two 8B loads (top/bot
//   row, contiguous 128B per 16-lane group in head-major value layout),
//   8 FMAs. Final shfl_xor(…,8) folds the x-pair; lanes idx<8 write.
// ---------------------------------------------------------------------------
__global__ __launch_bounds__(256) void msda_kernel(
    const unsigned short* __restrict__ off_bf,   // [kM][256] bf16 plain
    const unsigned short* __restrict__ attn_bf,  // [kM][128] bf16 plain
    const unsigned short* __restrict__ val_bf,   // [2*8][kS][32] bf16 head-major
    const float* __restrict__ priors,            // [kM][8]
    unsigned short* __restrict__ wgt)            // [kM][256] bf16 swizzled
{
  __shared__ int   s_mi[256 * 4];
  __shared__ float s_mw[256 * 4];
  const int q0 = blockIdx.x * 2;
  const int t = threadIdx.x;
  const int qh = t >> 4;          // qq*8 + h
  const int q = q0 + (qh >> 3);
  const int h = qh & 7;

  { // ---- phase 1 ----
    const int j = t & 15;
    const int lv = j >> 2;

    const float lgt = bf2f(attn_bf[(size_t)q * 128 + h * 16 + j]);
    float mx = lgt;
#pragma unroll
    for (int m = 8; m; m >>= 1) mx = fmaxf(mx, __shfl_xor(mx, m, 16));
    const float p = __expf(lgt - mx);
    float sum = p;
#pragma unroll
    for (int m = 8; m; m >>= 1) sum += __shfl_xor(sum, m, 16);
    const float wN = p / sum;

    const unsigned int oo = *(const unsigned int*)&off_bf[(size_t)q * 256 + (h * 16 + j) * 2];
    const float ox = bf2f((unsigned short)(oo & 0xffff));
    const float oy = bf2f((unsigned short)(oo >> 16));
    const float2 pr = *(const float2*)&priors[(size_t)q * 8 + lv * 2];

    const int Wl = 128 >> lv;
    const float fW = (float)Wl;
    const float lx = fmaf(pr.x, fW, ox) - 0.5f;
    const float ly = fmaf(pr.y, fW, oy) - 0.5f;
    const float x0f = floorf(lx), y0f = floorf(ly);
    const float wx1 = lx - x0f, wy1 = ly - y0f;
    const float wx0 = 1.f - wx1, wy0 = 1.f - wy1;
    const int x0 = (int)x0f, y0 = (int)y0f;
    const int start = (int)((0x5400500040000000ull >> (16 * lv)) & 0xffff); // {0,16384,20480,21504}

    const bool vx0 = (x0 >= 0) & (x0 < Wl);
    const bool vx1 = (x0 + 1 >= 0) & (x0 + 1 < Wl);
    const bool vy0 = (y0 >= 0) & (y0 < Wl);
    const bool vy1 = (y0 + 1 >= 0) & (y0 + 1 < Wl);
    const int xc0 = min(max(x0, 0), Wl - 1);
    const int xc1 = min(max(x0 + 1, 0), Wl - 1);
    const int yc0 = min(max(y0, 0), Wl - 1);
    const int yc1 = min(max(y0 + 1, 0), Wl - 1);

    const int off_top = (start + yc0 * Wl + xc0) * 64;   // bytes within head-plane
    const int off_bot = (start + yc1 * Wl + xc0) * 64;
    const int dx = (xc1 - xc0) * 64;

    const int slot = j * 16 + (qh ^ (j & 3));
    int4 mi; mi.x = off_top; mi.y = off_bot; mi.z = dx; mi.w = 0;
    *(int4*)&s_mi[slot * 4] = mi;
    float4 mw;
    mw.x = (vx0 & vy0) ? wN * wx0 * wy0 : 0.f;   // x0, top
    mw.y = (vx0 & vy1) ? wN * wx0 * wy1 : 0.f;   // x0, bot
    mw.z = (vx1 & vy0) ? wN * wx1 * wy0 : 0.f;   // x1, top
    mw.w = (vx1 & vy1) ? wN * wx1 * wy1 : 0.f;   // x1, bot
    *(float4*)&s_mw[slot * 4] = mw;
  }
  __syncthreads();

  // ---- phase 2 ----
  const int idx = t & 15;
  const int xsel = idx >> 3;      // 0: x0 corner, 1: x1 corner
  const int ch8 = idx & 7;        // 4 channels (8B) per lane
  const int b = (q >= kN) ? 1 : 0;
  const char* base = (const char*)val_bf + ((size_t)(b * 8 + h) * kS) * 64 + ch8 * 8;

  float a0 = 0.f, a1 = 0.f, a2 = 0.f, a3 = 0.f;
#pragma unroll
  for (int j = 0; j < 16; ++j) {
    const int slot = j * 16 + (qh ^ (j & 3));
    const int4 md = *(const int4*)&s_mi[slot * 4];
    const float2 wv = *(const float2*)&s_mw[slot * 4 + xsel * 2];
    const int dxs = xsel ? md.z : 0;
    const uint2 vt = *(const uint2*)(base + (md.x + dxs));
    const uint2 vb = *(const uint2*)(base + (md.y + dxs));
    a0 = fmaf(wv.x, __uint_as_float(vt.x << 16), a0);
    a1 = fmaf(wv.x, __uint_as_float(vt.x & 0xffff0000u), a1);
    a2 = fmaf(wv.x, __uint_as_float(vt.y << 16), a2);
    a3 = fmaf(wv.x, __uint_as_float(vt.y & 0xffff0000u), a3);
    a0 = fmaf(wv.y, __uint_as_float(vb.x << 16), a0);
    a1 = fmaf(wv.y, __uint_as_float(vb.x & 0xffff0000u), a1);
    a2 = fmaf(wv.y, __uint_as_float(vb.y << 16), a2);
    a3 = fmaf(wv.y, __uint_as_float(vb.y & 0xffff0000u), a3);
  }

  // fold the two x-corners (partner lane differs only in xsel)
  a0 += __shfl_xor(a0, 8, 16);
  a1 += __shfl_xor(a1, 8, 16);
  a2 += __shfl_xor(a2, 8, 16);
  a3 += __shfl_xor(a3, 8, 16);

  if (xsel == 0) {
    const int c0 = h * 32 + ch8 * 4;                    // ushort index in row
    const int dst = (c0 ^ ((q & 7) << 3));
    uint2 o;
    o.x = (unsigned int)f2bf(a0) | ((unsigned int)f2bf(a1) << 16);
    o.y = (unsigned int)f2bf(a2) | ((unsigned int)f2bf(a3) << 16);
    *(uint2*)&wgt[(size_t)q * 256 + dst] = o;
  }
}

// ---------------------------------------------------------------------------
// launch
// ---------------------------------------------------------------------------
extern "C" void kernel_launch(void* const* d_in, const int* in_sizes, int n_in,
                              void* d_out, int out_size, void* d_ws, size_t ws_size,
                              hipStream_t stream) {
  const float* in_feats = (const float*)d_in[0];
  const float* priors   = (const float*)d_in[1];
  const float* sfeats   = (const float*)d_in[2];
  const float* W_off  = (const float*)d_in[5];
  const float* b_off  = (const float*)d_in[6];
  const float* W_attn = (const float*)d_in[7];
  const float* b_attn = (const float*)d_in[8];
  const float* W_val  = (const float*)d_in[9];
  const float* b_val  = (const float*)d_in[10];
  const float* W_out  = (const float*)d_in[11];
  const float* b_out  = (const float*)d_in[12];
  float* out = (float*)d_out;

  // workspace (bf16 ushorts), ~123 MB total
  unsigned short* in_bf   = (unsigned short*)d_ws;          // kM*256 (swizzled)
  unsigned short* s_bf    = in_bf   + (size_t)kM * 256;     // kM*256 (swizzled)
  unsigned short* off_bf  = s_bf    + (size_t)kM * 256;     // kM*256 (plain)
  unsigned short* attn_bf = off_bf  + (size_t)kM * 256;     // kM*128 (plain)
  unsigned short* val_bf  = attn_bf + (size_t)kM * 128;     // [2*8][kS][32] head-major
  unsigned short* wgt_bf  = val_bf  + (size_t)kM * 256;     // kM*256 (swizzled)
  unsigned short* BtOff   = wgt_bf  + (size_t)kM * 256;     // 256*256
  unsigned short* BtAttn  = BtOff   + 256 * 256;            // 128*256
  unsigned short* BtVal   = BtAttn  + 128 * 256;            // 256*256
  unsigned short* BtOut   = BtVal   + 256 * 256;            // 256*256

  const dim3 blk(256);

  convert_act<<<dim3(kM * 32 * 2 / 256), blk, 0, stream>>>(in_feats, sfeats, in_bf, s_bf);
  prep_weights<<<dim3(896 * 32 / 256), blk, 0, stream>>>(
      W_off, W_attn, W_val, W_out, BtOff, BtAttn, BtVal, BtOut);

  gemm_bf16<1><<<dim3(kM / 128, 2), blk, 0, stream>>>(in_bf, BtOff, b_off, off_bf, 256);
  gemm_bf16<1><<<dim3(kM / 128, 1), blk, 0, stream>>>(in_bf, BtAttn, b_attn, attn_bf, 128);
  gemm_bf16<2><<<dim3(kM / 128, 2), blk, 0, stream>>>(s_bf, BtVal, b_val, val_bf, 256);

  msda_kernel<<<dim3(kM / 2), blk, 0, stream>>>(off_bf, attn_bf, val_bf, priors, wgt_bf);

  gemm_bf16<0><<<dim3(kM / 128, 2), blk, 0, stream>>>(wgt_bf, BtOut, b_out, out, 256);
}

// Round 4
// 152.623 us; speedup vs baseline: 4.6557x; 1.1802x over previous
//
#include <hip/hip_runtime.h>
#include <cstdint>

// Problem constants (fixed by setup_inputs)
constexpr int kB = 2;
constexpr int kN = 21760;
constexpr int kC = 256;
constexpr int kH = 8;
constexpr int kS = 21760;    // total sample-map area
constexpr int kM = kB * kN;  // 43520 rows

typedef __attribute__((ext_vector_type(8))) short bf16x8;   // MFMA A/B frag (4 VGPR)
typedef __attribute__((ext_vector_type(4))) float f32x4;    // MFMA C/D frag
typedef __attribute__((ext_vector_type(8))) unsigned short us8;

__device__ __forceinline__ float bf2f(unsigned short u) {
  return __uint_as_float(((unsigned int)u) << 16);
}
__device__ __forceinline__ unsigned short f2bf(float f) {
  unsigned int u = __float_as_uint(f);
  u += 0x7fffu + ((u >> 16) & 1u);
  return (unsigned short)(u >> 16);
}
__device__ __forceinline__ float blo(unsigned int v) { return __uint_as_float(v << 16); }
__device__ __forceinline__ float bhi(unsigned int v) { return __uint_as_float(v & 0xffff0000u); }
__device__ __forceinline__ void gld_lds16(const unsigned short* g, unsigned short* l) {
  __builtin_amdgcn_global_load_lds(
      (const __attribute__((address_space(1))) unsigned int*)g,
      (__attribute__((address_space(3))) unsigned int*)l, 16, 0, 0);
}

// ---------------------------------------------------------------------------
// Convert in_feats & sfeats f32 [kM][256] -> bf16, rows pre-swizzled for the
// GEMM LDS tile: element k goes to k ^ ((m&7)<<3).
// ---------------------------------------------------------------------------
__global__ __launch_bounds__(256) void convert_act(
    const float* __restrict__ a, const float* __restrict__ b,
    unsigned short* __restrict__ da, unsigned short* __restrict__ db)
{
  const int tid = blockIdx.x * 256 + threadIdx.x;
  const int half = kM * 32;
  const float* src; unsigned short* dst; int id;
  if (tid < half) { src = a; dst = da; id = tid; }
  else            { src = b; dst = db; id = tid - half; }
  const int m = id >> 5;
  const int kb = (id & 31) * 8;
  const float4 x0 = *(const float4*)&src[(size_t)m * 256 + kb];
  const float4 x1 = *(const float4*)&src[(size_t)m * 256 + kb + 4];
  us8 o;
  o[0] = f2bf(x0.x); o[1] = f2bf(x0.y); o[2] = f2bf(x0.z); o[3] = f2bf(x0.w);
  o[4] = f2bf(x1.x); o[5] = f2bf(x1.y); o[6] = f2bf(x1.z); o[7] = f2bf(x1.w);
  *(us8*)&dst[(size_t)m * 256 + (kb ^ ((m & 7) << 3))] = o;
}

// ---------------------------------------------------------------------------
// Weights: f32 [K=256][N] -> bf16 transposed [N][K], rows pre-swizzled.
// ---------------------------------------------------------------------------
__global__ __launch_bounds__(256) void prep_weights(
    const float* __restrict__ Woff, const float* __restrict__ Wattn,
    const float* __restrict__ Wval, const float* __restrict__ Wout,
    unsigned short* __restrict__ BtOff, unsigned short* __restrict__ BtAttn,
    unsigned short* __restrict__ BtVal, unsigned short* __restrict__ BtOut)
{
  const int tid = blockIdx.x * 256 + threadIdx.x;   // 896 rows * 32
  const int r = tid >> 5;
  const int kb = (tid & 31) * 8;
  const float* W; unsigned short* Bt; int n, Nn;
  if (r < 256)      { W = Woff;  Bt = BtOff;  n = r;       Nn = 256; }
  else if (r < 384) { W = Wattn; Bt = BtAttn; n = r - 256; Nn = 128; }
  else if (r < 640) { W = Wval;  Bt = BtVal;  n = r - 384; Nn = 256; }
  else              { W = Wout;  Bt = BtOut;  n = r - 640; Nn = 256; }
  us8 o;
#pragma unroll
  for (int i = 0; i < 8; ++i) o[i] = f2bf(W[(size_t)(kb + i) * Nn + n]);
  *(us8*)&Bt[(size_t)n * 256 + (kb ^ ((n & 7) << 3))] = o;
}

// ---------------------------------------------------------------------------
// bf16 MFMA GEMM: C[M,Nn] = A[M,256] @ Bt[Nn,256]^T + bias.
// OMODE: 0 = f32 plain out
//        1 = bf16 plain out
//        2 = bf16 head-major value layout [b, h, s, d]
//        3 = bf16 head-major attn logits [h][row][16]
//        4 = bf16 head-major offsets     [h][row][32]
// ---------------------------------------------------------------------------
template <int OMODE>
__global__ __launch_bounds__(256) void gemm_bf16(
    const unsigned short* __restrict__ A,
    const unsigned short* __restrict__ Bt,
    const float* __restrict__ bias,
    void* __restrict__ Cout, int Nn)
{
  __shared__ unsigned short As[128 * 64];
  __shared__ unsigned short Bs[128 * 64];
  const int t = threadIdx.x;
  const int w = t >> 6, l = t & 63;
  const int m0 = blockIdx.x * 128, n0 = blockIdx.y * 128;
  const int wm = w >> 1, wn = w & 1;

  f32x4 acc[4][4] = {};

  const int srow = l >> 3;
  const int skb  = (l & 7) * 8;

  for (int kt = 0; kt < 256; kt += 64) {
#pragma unroll
    for (int i = 0; i < 4; ++i) {
      const int c = i * 4 + w;
      const int row = c * 8 + srow;
      gld_lds16(A + (size_t)(m0 + row) * 256 + kt + skb, &As[c * 512]);
    }
#pragma unroll
    for (int i = 0; i < 4; ++i) {
      const int c = i * 4 + w;
      const int row = c * 8 + srow;
      gld_lds16(Bt + (size_t)(n0 + row) * 256 + kt + skb, &Bs[c * 512]);
    }
    __syncthreads();

#pragma unroll
    for (int s = 0; s < 2; ++s) {
      bf16x8 af[4], bfr[4];
      const int kf = s * 32 + ((l >> 4) * 8);
#pragma unroll
      for (int i = 0; i < 4; ++i) {
        const int row = wm * 64 + i * 16 + (l & 15);
        af[i] = *(const bf16x8*)&As[row * 64 + (kf ^ ((row & 7) << 3))];
      }
#pragma unroll
      for (int j = 0; j < 4; ++j) {
        const int col = wn * 64 + j * 16 + (l & 15);
        bfr[j] = *(const bf16x8*)&Bs[col * 64 + (kf ^ ((col & 7) << 3))];
      }
#pragma unroll
      for (int i = 0; i < 4; ++i)
#pragma unroll
        for (int j = 0; j < 4; ++j)
          acc[i][j] = __builtin_amdgcn_mfma_f32_16x16x32_bf16(af[i], bfr[j], acc[i][j], 0, 0, 0);
    }
    __syncthreads();
  }

  // epilogue: C/D map col = lane&15, row = (lane>>4)*4 + reg
  const int lr = l >> 4;
#pragma unroll
  for (int j = 0; j < 4; ++j) {
    const int col = n0 + wn * 64 + j * 16 + (l & 15);
    const float bv = bias[col];
#pragma unroll
    for (int i = 0; i < 4; ++i) {
      const int rbase = m0 + wm * 64 + i * 16 + lr * 4;
#pragma unroll
      for (int r = 0; r < 4; ++r) {
        const float v = acc[i][j][r] + bv;
        const int row = rbase + r;
        if (OMODE == 0) {
          ((float*)Cout)[(size_t)row * Nn + col] = v;
        } else if (OMODE == 1) {
          ((unsigned short*)Cout)[(size_t)row * Nn + col] = f2bf(v);
        } else if (OMODE == 2) {
          const int bb = row >= kS;
          const int s2 = row - bb * kS;
          ((unsigned short*)Cout)[((size_t)(bb * 8 + (col >> 5)) * kS + s2) * 32 + (col & 31)] = f2bf(v);
        } else if (OMODE == 3) {
          ((unsigned short*)Cout)[((size_t)(col >> 4) * kM + row) * 16 + (col & 15)] = f2bf(v);
        } else {
          ((unsigned short*)Cout)[((size_t)(col >> 5) * kM + row) * 32 + (col & 31)] = f2bf(v);
        }
      }
    }
  }
}

// ---------------------------------------------------------------------------
// MSDA core, plane-partitioned. Block = 16 queries x ONE (b,h) plane;
// grid = chunk*16 + plane, so plane p's blocks all land on XCD p&7
// (round-robin dispatch) -> per-XCD value working set = 2 planes = 2.8 MB,
// L2-resident.
// Phase 1: t = (ql = t>>4, j = t&15): softmax via 16-lane shfl_xor; folds
//   attn * bilinear * validity into 4 (byte-offset, weight) corner records
//   in LDS (q-stride 136 words -> conflict-free phase-2 b64 reads).
// Phase 2: t = (ql, lane): c = lane>>2 (corner), k = lane&3 (16B chunk).
//   Per sample: one ds_read_b64 (offset imm), one v_add, one
//   global_load_dwordx4 (SGPR plane base), 8 unpack + 8 FMA. Corner fold
//   via shfl_xor(4),(8); c==0 lanes write 16B to wgt (swizzled rows).
// ---------------------------------------------------------------------------
__global__ __launch_bounds__(256) void msda_kernel(
    const unsigned short* __restrict__ off_hm,   // [8][kM][32] bf16 head-major
    const unsigned short* __restrict__ attn_hm,  // [8][kM][16] bf16 head-major
    const unsigned short* __restrict__ val_bf,   // [16][kS][32] bf16 head-major
    const float* __restrict__ priors,            // [kM][8]
    unsigned short* __restrict__ wgt)            // [kM][256] bf16 swizzled
{
  __shared__ int s_rec[16 * 136];
  const int bid = blockIdx.x;
  const int plane = bid & 15;          // b*8 + h
  const int chunk = bid >> 4;
  const int b = plane >> 3, h = plane & 7;
  const int t = threadIdx.x;
  const int ql = t >> 4;
  const int q = b * kN + chunk * 16 + ql;

  { // ---- phase 1 ----
    const int j = t & 15;
    const int lv = j >> 2;

    const float lgt = bf2f(attn_hm[((size_t)h * kM + q) * 16 + j]);
    float mx = lgt;
#pragma unroll
    for (int m = 8; m; m >>= 1) mx = fmaxf(mx, __shfl_xor(mx, m, 16));
    const float p = __expf(lgt - mx);
    float sum = p;
#pragma unroll
    for (int m = 8; m; m >>= 1) sum += __shfl_xor(sum, m, 16);
    const float wN = p / sum;

    const unsigned int oo = *(const unsigned int*)&off_hm[((size_t)h * kM + q) * 32 + j * 2];
    const float ox = blo(oo);
    const float oy = bhi(oo);
    const float2 pr = *(const float2*)&priors[(size_t)q * 8 + lv * 2];

    const int Wl = 128 >> lv;
    const float fW = (float)Wl;
    const float lx = fmaf(pr.x, fW, ox) - 0.5f;
    const float ly = fmaf(pr.y, fW, oy) - 0.5f;
    const float x0f = floorf(lx), y0f = floorf(ly);
    const float wx1 = lx - x0f, wy1 = ly - y0f;
    const float wx0 = 1.f - wx1, wy0 = 1.f - wy1;
    const int x0 = (int)x0f, y0 = (int)y0f;
    const int start = (int)((0x5400500040000000ull >> (16 * lv)) & 0xffff); // {0,16384,20480,21504}

    const bool vx0 = (x0 >= 0) & (x0 < Wl);
    const bool vx1 = (x0 + 1 >= 0) & (x0 + 1 < Wl);
    const bool vy0 = (y0 >= 0) & (y0 < Wl);
    const bool vy1 = (y0 + 1 >= 0) & (y0 + 1 < Wl);
    const int xc0 = min(max(x0, 0), Wl - 1);
    const int xc1 = min(max(x0 + 1, 0), Wl - 1);
    const int yc0 = min(max(y0, 0), Wl - 1);
    const int yc1 = min(max(y0 + 1, 0), Wl - 1);

    const int rt = start + yc0 * Wl;   // row bases (elements)
    const int rb = start + yc1 * Wl;

    int4 r0, r1;
    r0.x = (rt + xc0) * 64; r0.y = __float_as_int((vx0 & vy0) ? wN * wx0 * wy0 : 0.f);
    r0.z = (rt + xc1) * 64; r0.w = __float_as_int((vx1 & vy0) ? wN * wx1 * wy0 : 0.f);
    r1.x = (rb + xc0) * 64; r1.y = __float_as_int((vx0 & vy1) ? wN * wx0 * wy1 : 0.f);
    r1.z = (rb + xc1) * 64; r1.w = __float_as_int((vx1 & vy1) ? wN * wx1 * wy1 : 0.f);

    const int base = ql * 136 + j * 8;
    *(int4*)&s_rec[base] = r0;
    *(int4*)&s_rec[base + 4] = r1;
  }
  __syncthreads();

  // ---- phase 2 ----
  const int lane = t & 15;
  const int c = lane >> 2;        // corner: 0=TL 1=TR 2=BL 3=BR
  const int k = lane & 3;         // 16B chunk (8 channels)
  const char* plane_base = (const char*)val_bf + (size_t)plane * kS * 64 + k * 16;
  const int* rp = &s_rec[ql * 136 + c * 2];

  float a0 = 0.f, a1 = 0.f, a2 = 0.f, a3 = 0.f;
  float a4 = 0.f, a5 = 0.f, a6 = 0.f, a7 = 0.f;
#pragma unroll
  for (int j = 0; j < 16; ++j) {
    const int2 r = *(const int2*)&rp[j * 8];
    const float w = __int_as_float(r.y);
    const uint4 v = *(const uint4*)(plane_base + r.x);
    a0 = fmaf(w, blo(v.x), a0); a1 = fmaf(w, bhi(v.x), a1);
    a2 = fmaf(w, blo(v.y), a2); a3 = fmaf(w, bhi(v.y), a3);
    a4 = fmaf(w, blo(v.z), a4); a5 = fmaf(w, bhi(v.z), a5);
    a6 = fmaf(w, blo(v.w), a6); a7 = fmaf(w, bhi(v.w), a7);
  }

  // fold the 4 corners (lane bits 2-3)
#pragma unroll
  for (int m = 4; m <= 8; m <<= 1) {
    a0 += __shfl_xor(a0, m); a1 += __shfl_xor(a1, m);
    a2 += __shfl_xor(a2, m); a3 += __shfl_xor(a3, m);
    a4 += __shfl_xor(a4, m); a5 += __shfl_xor(a5, m);
    a6 += __shfl_xor(a6, m); a7 += __shfl_xor(a7, m);
  }

  if (c == 0) {
    const int c0 = h * 32 + k * 8;                    // ushort index in row
    const int dst = c0 ^ ((q & 7) << 3);
    uint4 o;
    o.x = (unsigned int)f2bf(a0) | ((unsigned int)f2bf(a1) << 16);
    o.y = (unsigned int)f2bf(a2) | ((unsigned int)f2bf(a3) << 16);
    o.z = (unsigned int)f2bf(a4) | ((unsigned int)f2bf(a5) << 16);
    o.w = (unsigned int)f2bf(a6) | ((unsigned int)f2bf(a7) << 16);
    *(uint4*)&wgt[(size_t)q * 256 + dst] = o;
  }
}

// ---------------------------------------------------------------------------
// launch
// ---------------------------------------------------------------------------
extern "C" void kernel_launch(void* const* d_in, const int* in_sizes, int n_in,
                              void* d_out, int out_size, void* d_ws, size_t ws_size,
                              hipStream_t stream) {
  const float* in_feats = (const float*)d_in[0];
  const float* priors   = (const float*)d_in[1];
  const float* sfeats   = (const float*)d_in[2];
  const float* W_off  = (const float*)d_in[5];
  const float* b_off  = (const float*)d_in[6];
  const float* W_attn = (const float*)d_in[7];
  const float* b_attn = (const float*)d_in[8];
  const float* W_val  = (const float*)d_in[9];
  const float* b_val  = (const float*)d_in[10];
  const float* W_out  = (const float*)d_in[11];
  const float* b_out  = (const float*)d_in[12];
  float* out = (float*)d_out;

  // workspace (bf16 ushorts), ~123 MB total
  unsigned short* in_bf   = (unsigned short*)d_ws;          // kM*256 (swizzled)
  unsigned short* s_bf    = in_bf   + (size_t)kM * 256;     // kM*256 (swizzled)
  unsigned short* off_bf  = s_bf    + (size_t)kM * 256;     // [8][kM][32] head-major
  unsigned short* attn_bf = off_bf  + (size_t)kM * 256;     // [8][kM][16] head-major
  unsigned short* val_bf  = attn_bf + (size_t)kM * 128;     // [16][kS][32] head-major
  unsigned short* wgt_bf  = val_bf  + (size_t)kM * 256;     // kM*256 (swizzled)
  unsigned short* BtOff   = wgt_bf  + (size_t)kM * 256;     // 256*256
  unsigned short* BtAttn  = BtOff   + 256 * 256;            // 128*256
  unsigned short* BtVal   = BtAttn  + 128 * 256;            // 256*256
  unsigned short* BtOut   = BtVal   + 256 * 256;            // 256*256

  const dim3 blk(256);

  convert_act<<<dim3(kM * 32 * 2 / 256), blk, 0, stream>>>(in_feats, sfeats, in_bf, s_bf);
  prep_weights<<<dim3(896 * 32 / 256), blk, 0, stream>>>(
      W_off, W_attn, W_val, W_out, BtOff, BtAttn, BtVal, BtOut);

  gemm_bf16<4><<<dim3(kM / 128, 2), blk, 0, stream>>>(in_bf, BtOff, b_off, off_bf, 256);
  gemm_bf16<3><<<dim3(kM / 128, 1), blk, 0, stream>>>(in_bf, BtAttn, b_attn, attn_bf, 128);
  gemm_bf16<2><<<dim3(kM / 128, 2), blk, 0, stream>>>(s_bf, BtVal, b_val, val_bf, 256);

  msda_kernel<<<dim3(kM / 2), blk, 0, stream>>>(off_bf, attn_bf, val_bf, priors, wgt_bf);

  gemm_bf16<0><<<dim3(kM / 128, 2), blk, 0, stream>>>(wgt_bf, BtOut, b_out, out, 256);
}